// Round 12
// baseline (52.456 us; speedup 1.0000x reference)
//
#include <hip/hip_runtime.h>

#define NB   16
#define NC   3
#define NH   512
#define NW   512
#define OUTH 506
#define OUTW 506
#define NCHK 18          // 16 chunks x 28 rows + 2 chunks x 29 rows = 506
#define NSLOT 10         // wave-private ring slots
#define NBLK (NB * NC * NCHK * 2)   // 1728 one-wave blocks (~6.75/CU, all resident)
#define BPI  (NC * NCHK * 2)        // 108 partials per image
#define MMB  64                     // minmax partial blocks per image

// -------- kernel 1: per-image min/max partials (no atomics)
__global__ __launch_bounds__(256) void ssim_minmax(const float* __restrict__ pred,
                                                   float* __restrict__ mnp,
                                                   float* __restrict__ mxp) {
    int b = blockIdx.y;
    const float4* p4 = (const float4*)(pred + (size_t)b * (NC * NH * NW));
    const int n4 = (NC * NH * NW) / 4;
    float lmin = 3.4e38f, lmax = -3.4e38f;
    for (int i = blockIdx.x * blockDim.x + threadIdx.x; i < n4; i += gridDim.x * blockDim.x) {
        float4 v = p4[i];
        lmin = fminf(lmin, fminf(fminf(v.x, v.y), fminf(v.z, v.w)));
        lmax = fmaxf(lmax, fmaxf(fmaxf(v.x, v.y), fmaxf(v.z, v.w)));
    }
    #pragma unroll
    for (int off = 32; off; off >>= 1) {
        lmin = fminf(lmin, __shfl_down(lmin, off, 64));
        lmax = fmaxf(lmax, __shfl_down(lmax, off, 64));
    }
    __shared__ float smin[4], smax[4];
    int wid = threadIdx.x >> 6, lane = threadIdx.x & 63;
    if (lane == 0) { smin[wid] = lmin; smax[wid] = lmax; }
    __syncthreads();
    if (threadIdx.x == 0) {
        mnp[b * MMB + blockIdx.x] = fminf(fminf(smin[0], smin[1]), fminf(smin[2], smin[3]));
        mxp[b * MMB + blockIdx.x] = fmaxf(fmaxf(smax[0], smax[1]), fmaxf(smax[2], smax[3]));
    }
}

// -------- kernel 2: barrier-free 1-wave LDS-ring SSIM
// Task = (imgch, 28/29-row chunk, 256-col half). Wave-private ring
// [10][2][264] = 21,120 B -> 7 blocks/CU; no __syncthreads in the loop
// (same-wave DS ordering + runtime-disjoint slots => race-free).
// Thread owns 4 output cols, tracks 10 via 3 aligned b128 reads/array.
// Pipeline at iter k: stage row k+2 (loaded iter k-2) -> load row k+4;
// enter row k from regs (prefetched iter k-1) -> prefetch row k+1;
// leave row k-7 from regs -> prefetch row k-6; emit row k-6.
__global__ __launch_bounds__(64) void ssim_main(const float* __restrict__ tin,
                                                const float* __restrict__ pin,
                                                const float* __restrict__ mnp,
                                                const float* __restrict__ mxp,
                                                float* __restrict__ bsum) {
    __shared__ float ring[NSLOT][2][264];   // 21,120 B

    const int li    = threadIdx.x;          // 0..63
    const int task  = blockIdx.x;
    const int imgch = task / (NCHK * 2);
    const int rem   = task - imgch * (NCHK * 2);
    const int chunk = rem >> 1;
    const int half  = rem & 1;
    const int b     = imgch / NC;
    const int r0    = chunk * 28 + max(0, chunk - 16);  // chunks 16,17: 29 rows
    const int rpc   = (chunk >= 16) ? 29 : 28;
    const int kend  = rpc + 6;
    const int lastr = rpc + 5;
    const int gcol0 = half * 256;

    // per-image range: 64 partials == 64 lanes, butterfly (no LDS)
    float mnv = mnp[b * MMB + li], mxv = mxp[b * MMB + li];
    #pragma unroll
    for (int m = 1; m < 64; m <<= 1) {
        mnv = fminf(mnv, __shfl_xor(mnv, m, 64));
        mxv = fmaxf(mxv, __shfl_xor(mxv, m, 64));
    }
    const float dr  = mxv - mnv;
    const float c1  = (0.01f * dr) * (0.01f * dr);
    const float c2  = (0.03f * dr) * (0.03f * dr);
    const float C1s = 2401.0f * c1;   // 49^2 * c1
    const float C2s = 2352.0f * c2;   // 48*49 * c2

    const float* tbase = tin + (size_t)imgch * (NH * NW) + (size_t)r0 * NW;
    const float* pbase = pin + (size_t)imgch * (NH * NW) + (size_t)r0 * NW;

    // ---- staging plan: one ring row = [2][264] = 132 b128 (t: 0..65, p: 66..131)
    // thread li stages b128 #li and #(li+64); threads 0..3 also #(li+128)
    const int s0i = li, s1i = li + 64, s2i = li + 128;
    const int a0 = (s0i >= 66) ? 1 : 0;
    const int a1 = (s1i >= 66) ? 1 : 0;
    const int c0i = (s0i - a0 * 66) * 4;
    const int c1i = (s1i - a1 * 66) * 4;
    const int c2i = (s2i - 66) * 4;
    const float* gp0 = (a0 ? pbase : tbase) + min(gcol0 + c0i, NW - 4);
    const float* gp1 = (a1 ? pbase : tbase) + min(gcol0 + c1i, NW - 4);
    const float* gp2 = pbase + min(gcol0 + c2i, NW - 4);
    const int w0 = s0i * 16, w1 = s1i * 16, w2 = s2i * 16;  // byte offs in slot
    const bool has3 = (li < 4);

    // ---- compute ownership: local cols rc..rc+9 tracked (own rc..rc+3)
    const int rc   = 4 * li;
    const int cmax = half ? 252 : 260;         // clamp only affects masked outputs
    const int cb1  = min(rc + 4, cmax);
    const int cb2  = min(rc + 8, cmax);
    const int oc   = gcol0 + rc;               // global output col base

    float v1[10], v2[10], v3[10], v4[10], v5[10];
    #pragma unroll
    for (int i = 0; i < 10; ++i) { v1[i]=0.f; v2[i]=0.f; v3[i]=0.f; v4[i]=0.f; v5[i]=0.f; }

    float acc = 0.f;

#define GLOAD(K, G0, G1, G2) do {                                   \
        G0 = *(const float4*)(gp0 + (size_t)(K) * NW);              \
        G1 = *(const float4*)(gp1 + (size_t)(K) * NW);              \
        if (has3) G2 = *(const float4*)(gp2 + (size_t)(K) * NW);    \
    } while (0)

#define STAGE(S, G0, G1, G2) do {                                   \
        char* _rb = (char*)&ring[S][0][0];                          \
        *(float4*)(_rb + w0) = G0;                                  \
        *(float4*)(_rb + w1) = G1;                                  \
        if (has3) *(float4*)(_rb + w2) = G2;                        \
    } while (0)

#define LOADT(TE, PE, S) do {                                       \
        *(float4*)&TE[0] = *(const float4*)&ring[S][0][rc];         \
        *(float4*)&TE[4] = *(const float4*)&ring[S][0][cb1];        \
        *(float4*)&TE[8] = *(const float4*)&ring[S][0][cb2];        \
        *(float4*)&PE[0] = *(const float4*)&ring[S][1][rc];         \
        *(float4*)&PE[4] = *(const float4*)&ring[S][1][cb1];        \
        *(float4*)&PE[8] = *(const float4*)&ring[S][1][cb2];        \
    } while (0)

#define APPLY(TE, PE, SGN) do {                                     \
        _Pragma("unroll")                                           \
        for (int i = 0; i < 10; ++i) {                              \
            float t_ = TE[i], p_ = PE[i];                           \
            v1[i] += SGN t_;  v2[i] += SGN p_;                      \
            v3[i] = fmaf(SGN t_, t_, v3[i]);                        \
            v4[i] = fmaf(SGN p_, p_, v4[i]);                        \
            v5[i] = fmaf(SGN t_, p_, v5[i]);                        \
        }                                                           \
    } while (0)

#define SSIMADD(C) do {                                             \
        if (oc + (C) < OUTW) {                                      \
            float p12 = S1 * S2;                                    \
            float q1  = S1 * S1, q2 = S2 * S2;                      \
            float A1  = fmaf(2.f, p12, C1s);                        \
            float B1  = q1 + q2 + C1s;                              \
            float mtp = fmaf(49.f, S5, -p12);                       \
            float A2  = fmaf(2.f, mtp, C2s);                        \
            float mtt = fmaf(49.f, S3, -q1);                        \
            float mpp = fmaf(49.f, S4, -q2);                        \
            float B2  = mtt + mpp + C2s;                            \
            acc += __fdividef(A1 * A2, B1 * B2);                    \
        }                                                           \
    } while (0)

#define EMIT do {                                                   \
        float S1 = v1[0]+v1[1]+v1[2]+v1[3]+v1[4]+v1[5]+v1[6];       \
        float S2 = v2[0]+v2[1]+v2[2]+v2[3]+v2[4]+v2[5]+v2[6];       \
        float S3 = v3[0]+v3[1]+v3[2]+v3[3]+v3[4]+v3[5]+v3[6];       \
        float S4 = v4[0]+v4[1]+v4[2]+v4[3]+v4[4]+v4[5]+v4[6];       \
        float S5 = v5[0]+v5[1]+v5[2]+v5[3]+v5[4]+v5[5]+v5[6];       \
        SSIMADD(0);                                                 \
        _Pragma("unroll")                                           \
        for (int c = 1; c < 4; ++c) {                               \
            S1 += v1[c+6] - v1[c-1];                                \
            S2 += v2[c+6] - v2[c-1];                                \
            S3 += v3[c+6] - v3[c-1];                                \
            S4 += v4[c+6] - v4[c-1];                                \
            S5 += v5[c+6] - v5[c-1];                                \
            SSIMADD(c);                                             \
        }                                                           \
    } while (0)

    // ---- prologue: rows 0,1 staged; rows 2,3 in flight (gA, gB)
    float4 gA0, gA1, gA2, gB0, gB1, gB2;
    GLOAD(0, gA0, gA1, gA2); STAGE(0, gA0, gA1, gA2);
    GLOAD(1, gA0, gA1, gA2); STAGE(1, gA0, gA1, gA2);
    GLOAD(2, gA0, gA1, gA2);          // written at iter 0 (slot 2)
    GLOAD(3, gB0, gB1, gB2);          // written at iter 1 (slot 3)

    float et[12], ep[12], lt[12], lp[12];
    LOADT(et, ep, 0);                 // enter row 0 prefetch

    int sn = 1, sw = 2, slv = 4;      // (k+1)%10, (k+2)%10, (k+4)%10

#define STEP(K, G0, G1, G2) do {                                    \
        /* 1) stage row K+2 (loaded at iter K-2) */                 \
        if ((K) + 2 <= lastr) STAGE(sw, G0, G1, G2);                \
        /* 2) load row K+4 into same set (2-iter flight) */         \
        if ((K) + 4 <= lastr) GLOAD((K) + 4, G0, G1, G2);           \
        /* 3) enter row K from prefetched regs */                   \
        APPLY(et, ep, +);                                           \
        /* 4) prefetch enter row K+1 (written at iter K-1) */       \
        if ((K) + 1 < kend) LOADT(et, ep, sn);                      \
        /* 5) leave row K-7 from prefetched regs */                 \
        if ((K) >= 7) APPLY(lt, lp, -);                             \
        /* 6) prefetch leave row K-6 (= next iter's K-7) */         \
        if ((K) >= 6) LOADT(lt, lp, slv);                           \
        /* 7) emit output row K-6 */                                \
        if ((K) >= 6) { EMIT; }                                     \
        /* 8) advance slot counters */                              \
        if (++sn  == NSLOT) sn  = 0;                                \
        if (++sw  == NSLOT) sw  = 0;                                \
        if (++slv == NSLOT) slv = 0;                                \
    } while (0)

    int k = 0;
    while (true) {
        STEP(k, gA0, gA1, gA2); if (++k >= kend) break;
        STEP(k, gB0, gB1, gB2); if (++k >= kend) break;
    }

#undef STEP
#undef EMIT
#undef SSIMADD
#undef APPLY
#undef LOADT
#undef STAGE
#undef GLOAD

    // per-block partial (deterministic)
    #pragma unroll
    for (int off = 32; off; off >>= 1) acc += __shfl_down(acc, off, 64);
    if (li == 0) bsum[task] = acc;
}

// -------- kernel 3: finalize per-image mean from 108 block partials
__global__ void ssim_finalize(const float* __restrict__ bsum, float* __restrict__ out) {
    int b = blockIdx.x, lane = threadIdx.x;   // 64 threads
    float v = 0.f;
    for (int i = lane; i < BPI; i += 64) v += bsum[b * BPI + i];
    #pragma unroll
    for (int off = 32; off; off >>= 1) v += __shfl_down(v, off, 64);
    if (lane == 0) out[b] = v / (float)(NC * OUTH * OUTW);
}

extern "C" void kernel_launch(void* const* d_in, const int* in_sizes, int n_in,
                              void* d_out, int out_size, void* d_ws, size_t ws_size,
                              hipStream_t stream) {
    const float* t = (const float*)d_in[0];   // true
    const float* p = (const float*)d_in[1];   // pred
    float* out = (float*)d_out;

    float* mnp  = (float*)d_ws;               // 1024 floats
    float* mxp  = mnp + NB * MMB;             // 1024 floats
    float* bsum = mxp + NB * MMB;             // 1728 floats

    ssim_minmax<<<dim3(MMB, NB), 256, 0, stream>>>(p, mnp, mxp);
    // 1728 one-wave blocks (16 img x 3 ch x 18 chunks x 2 col-halves)
    ssim_main<<<dim3(NBLK), 64, 0, stream>>>(t, p, mnp, mxp, bsum);
    ssim_finalize<<<dim3(NB), 64, 0, stream>>>(bsum, out);
}